// Round 2
// baseline (135.647 us; speedup 1.0000x reference)
//
#include <hip/hip_runtime.h>
#include <hip/hip_bf16.h>

// Reduced problem: out[n] depends only on x0 = node_vec[:, :128], emb, W1_l0[:, :, :128],
// b1[:128], W2, b2, W3, b3, W4, b4.  y1/y2/gates are dead code in the reference.

#define KTOT 2048           // 128*16 contraction length
#define NKC  64             // KTOT/32 K-steps for 16x16x32 MFMA

typedef __bf16 bf16x8 __attribute__((ext_vector_type(8)));
typedef float  f32x4  __attribute__((ext_vector_type(4)));

static __device__ __forceinline__ unsigned short f2bf(float f) {
    unsigned int u = __builtin_bit_cast(unsigned int, f);
    return (unsigned short)((u + 0x8000u) >> 16);   // round-half-up, bias negligible
}
static __device__ __forceinline__ float bf2f(unsigned short h) {
    unsigned int u = ((unsigned int)h) << 16;
    return __builtin_bit_cast(float, u);
}
static __device__ __forceinline__ unsigned int pack2(float a, float b) {
    unsigned int ua = __builtin_bit_cast(unsigned int, a);
    unsigned int ub = __builtin_bit_cast(unsigned int, b);
    return ((ua + 0x8000u) >> 16) | ((ub + 0x8000u) & 0xFFFF0000u); // low=a, high=b
}
static __device__ __forceinline__ f32x4 mfma16(uint4 a, uint4 b, f32x4 c) {
    return __builtin_amdgcn_mfma_f32_16x16x32_bf16(
        __builtin_bit_cast(bf16x8, a), __builtin_bit_cast(bf16x8, b), c, 0, 0, 0);
}

// ---------------------------------------------------------------------------
// Prep: convert W1_l0 (rows K=i*16+a of 224 cols, keep cols 0..127) and W2
// (rows K x 16) to bf16 in B-fragment order:
//   W1T[kc][t][lane][j] = bf16(W1[K = kc*32 + (lane>>4)*8 + j][t*16 + (lane&15)])
//   W2T[kc][lane][j]    = bf16(W2[K][lane&15])
// ---------------------------------------------------------------------------
__global__ __launch_bounds__(256) void prep_kernel(
        const float* __restrict__ W1, const float* __restrict__ W2,
        unsigned short* __restrict__ W1T, unsigned short* __restrict__ W2T) {
    const int kc  = blockIdx.x;   // 0..63
    const int tid = threadIdx.x;
    __shared__ float l1[32 * 128];
    __shared__ float l2[32 * 16];

    for (int idx = tid; idx < 32 * 32; idx += 256) {       // 32 rows x 32 float4
        int row = idx >> 5, c4 = idx & 31;
        float4 v = *(const float4*)(W1 + (size_t)(kc * 32 + row) * 224 + c4 * 4);
        *(float4*)(l1 + row * 128 + c4 * 4) = v;
    }
    for (int idx = tid; idx < 32 * 4; idx += 256) {        // 32 rows x 4 float4
        int row = idx >> 2, c4 = idx & 3;
        float4 v = *(const float4*)(W2 + (size_t)(kc * 32 + row) * 16 + c4 * 4);
        *(float4*)(l2 + row * 16 + c4 * 4) = v;
    }
    __syncthreads();

    for (int pr = tid; pr < 512; pr += 256) {              // pr = t*64 + lane
        int t = pr >> 6, lane = pr & 63, q = lane >> 4, c = lane & 15;
        unsigned int w[4];
#pragma unroll
        for (int jj = 0; jj < 4; ++jj) {
            float a = l1[(q * 8 + 2 * jj    ) * 128 + t * 16 + c];
            float b = l1[(q * 8 + 2 * jj + 1) * 128 + t * 16 + c];
            w[jj] = pack2(a, b);
        }
        *(uint4*)(W1T + (size_t)kc * 4096 + pr * 8) = make_uint4(w[0], w[1], w[2], w[3]);
    }
    if (tid < 64) {
        int lane = tid, q = lane >> 4, c = lane & 15;
        unsigned int w[4];
#pragma unroll
        for (int jj = 0; jj < 4; ++jj) {
            float a = l2[(q * 8 + 2 * jj    ) * 16 + c];
            float b = l2[(q * 8 + 2 * jj + 1) * 16 + c];
            w[jj] = pack2(a, b);
        }
        *(uint4*)(W2T + (size_t)kc * 512 + lane * 8) = make_uint4(w[0], w[1], w[2], w[3]);
    }
}

// ---------------------------------------------------------------------------
// Main fused kernel: 64 nodes/block, 4 waves, each wave 16 nodes x 128 cols.
// A-frag built in registers: p[m][K=kc*32+q*8+j] = x0[m, 2kc+(q>>1)] * emb[m, (q&1)*8+j]
// ---------------------------------------------------------------------------
#define P1_STEP(BB, XV)                                                        \
    {                                                                          \
        float xv_ = (XV);                                                      \
        uint4 af_ = make_uint4(pack2(xv_ * e[0], xv_ * e[1]),                  \
                               pack2(xv_ * e[2], xv_ * e[3]),                  \
                               pack2(xv_ * e[4], xv_ * e[5]),                  \
                               pack2(xv_ * e[6], xv_ * e[7]));                 \
        acc[0] = mfma16(af_, BB[0], acc[0]);                                   \
        acc[1] = mfma16(af_, BB[1], acc[1]);                                   \
        acc[2] = mfma16(af_, BB[2], acc[2]);                                   \
        acc[3] = mfma16(af_, BB[3], acc[3]);                                   \
        acc[4] = mfma16(af_, BB[4], acc[4]);                                   \
        acc[5] = mfma16(af_, BB[5], acc[5]);                                   \
        acc[6] = mfma16(af_, BB[6], acc[6]);                                   \
        acc[7] = mfma16(af_, BB[7], acc[7]);                                   \
    }

#define P2_STEP(WB, SV)                                                        \
    {                                                                          \
        float sv_ = (SV);                                                      \
        uint4 af_ = make_uint4(pack2(sv_ * e[0], sv_ * e[1]),                  \
                               pack2(sv_ * e[2], sv_ * e[3]),                  \
                               pack2(sv_ * e[4], sv_ * e[5]),                  \
                               pack2(sv_ * e[6], sv_ * e[7]));                 \
        macc = mfma16(af_, WB, macc);                                          \
    }

__global__ __launch_bounds__(256) void main_kernel(
        const float* __restrict__ node_vec, const float* __restrict__ emb,
        const unsigned short* __restrict__ W1T, const unsigned short* __restrict__ W2T,
        const float* __restrict__ b1, const float* __restrict__ b2,
        const float* __restrict__ W3, const float* __restrict__ b3,
        const float* __restrict__ W4, const float* __restrict__ b4,
        float* __restrict__ out) {
    const int tid  = threadIdx.x;
    const int wave = tid >> 6, lane = tid & 63;
    const int q = lane >> 4, c = lane & 15;
    const int ihalf = q >> 1;
    const int nodeBase = blockIdx.x * 64;

    __shared__ float          x0s[64 * 132];   // x0 tile fp32, stride 132
    __shared__ unsigned short scs[64 * 136];   // silu(s0) bf16, stride 136
    __shared__ float          mids[64 * 17];
    __shared__ float          w3s[256];
    __shared__ float          b3s[16];
    __shared__ float          w4s[16];
    __shared__ float          b4s[1];

    // stage x0 (cols 0..127 of node_vec rows) as fp32
    for (int idx = tid; idx < 64 * 32; idx += 256) {
        int row = idx >> 5, c4 = idx & 31;
        float4 v = *(const float4*)(node_vec + (size_t)(nodeBase + row) * 480 + c4 * 4);
        *(float4*)(x0s + row * 132 + c4 * 4) = v;
    }
    w3s[tid & 255] = W3[tid & 255];
    if (tid < 16) { b3s[tid] = b3[tid]; w4s[tid] = W4[tid]; }
    if (tid == 0) b4s[0] = b4[0];

    // per-lane emb slice: node = nodeBase + wave*16 + c, a-range = (q&1)*8 .. +8
    float e[8];
    {
        const float* ep = emb + (size_t)(nodeBase + wave * 16 + c) * 16 + (q & 1) * 8;
        float4 v0 = *(const float4*)ep;
        float4 v1 = *(const float4*)(ep + 4);
        e[0] = v0.x; e[1] = v0.y; e[2] = v0.z; e[3] = v0.w;
        e[4] = v1.x; e[5] = v1.y; e[6] = v1.z; e[7] = v1.w;
    }
    __syncthreads();

    // ---------------- Phase 1: s0 = (x0 (x) emb) @ W1T, 16 nodes x 128 cols/wave
    f32x4 acc[8];
#pragma unroll
    for (int t = 0; t < 8; ++t) acc[t] = (f32x4){0.f, 0.f, 0.f, 0.f};

    const int rowA = wave * 16 + c;                // A-operand node (m = lane&15)
    const uint4* bptr = (const uint4*)W1T + lane;  // + (kc*8+t)*64

    uint4 bb0[8], bb1[8];
    float xs0, xs1;
#pragma unroll
    for (int t = 0; t < 8; ++t) bb0[t] = bptr[t * 64];
    xs0 = x0s[rowA * 132 + ihalf];

    for (int kc = 0; kc < NKC; kc += 2) {
        const int k1 = kc + 1;
#pragma unroll
        for (int t = 0; t < 8; ++t) bb1[t] = bptr[(k1 * 8 + t) * 64];
        xs1 = x0s[rowA * 132 + 2 * k1 + ihalf];
        P1_STEP(bb0, xs0);
        const int k2 = (kc + 2 < NKC) ? kc + 2 : 0;
#pragma unroll
        for (int t = 0; t < 8; ++t) bb0[t] = bptr[(k2 * 8 + t) * 64];
        xs0 = x0s[rowA * 132 + 2 * k2 + ihalf];
        P1_STEP(bb1, xs1);
    }

    // epilogue: s -> silu -> bf16 LDS   (C layout: col = lane&15, row = q*4+reg)
    const float inv2048 = 0.022097086912079608f;   // 1/sqrt(128*16)
    float bb1v[8];
#pragma unroll
    for (int t = 0; t < 8; ++t) bb1v[t] = b1[t * 16 + c];
#pragma unroll
    for (int t = 0; t < 8; ++t) {
#pragma unroll
        for (int r = 0; r < 4; ++r) {
            int node = wave * 16 + q * 4 + r;
            float s  = acc[t][r] * inv2048 + bb1v[t];
            float sc = s / (1.f + __expf(-s));
            scs[node * 136 + t * 16 + c] = f2bf(sc);
        }
    }
    __syncthreads();

    // ---------------- Phase 2: mid = (silu(s0) (x) emb) @ W2T, 16 nodes x 16 cols/wave
    f32x4 macc = (f32x4){0.f, 0.f, 0.f, 0.f};
    const uint4* b2p = (const uint4*)W2T + lane;   // + kc*64
    const int rowS = wave * 16 + c;
    uint4 wb0, wb1;
    float ss0, ss1;
    wb0 = b2p[0];
    ss0 = bf2f(scs[rowS * 136 + ihalf]);
    for (int kc = 0; kc < NKC; kc += 2) {
        const int k1 = kc + 1;
        wb1 = b2p[k1 * 64];
        ss1 = bf2f(scs[rowS * 136 + 2 * k1 + ihalf]);
        P2_STEP(wb0, ss0);
        const int k2 = (kc + 2 < NKC) ? kc + 2 : 0;
        wb0 = b2p[k2 * 64];
        ss0 = bf2f(scs[rowS * 136 + 2 * k2 + ihalf]);
        P2_STEP(wb1, ss1);
    }
    {
        float bb2 = b2[c];
#pragma unroll
        for (int r = 0; r < 4; ++r) {
            int node = wave * 16 + q * 4 + r;
            mids[node * 17 + c] = macc[r] * inv2048 + bb2;
        }
    }
    __syncthreads();

    // ---------------- Phase 3: h = silu(mid@W3/4 + b3); out = h@W4/4 + b4
    {
        int n = tid >> 2, part = tid & 3;
        float m[16];
#pragma unroll
        for (int cc = 0; cc < 16; ++cc) m[cc] = mids[n * 17 + cc];
        float po = 0.f;
#pragma unroll
        for (int j = 0; j < 4; ++j) {
            int jj = part * 4 + j;
            float a = 0.f;
#pragma unroll
            for (int cc = 0; cc < 16; ++cc) a += m[cc] * w3s[cc * 16 + jj];
            a = a * 0.25f + b3s[jj];
            float hh = a / (1.f + __expf(-a));
            po += hh * w4s[jj];
        }
        po += __shfl_xor(po, 1);
        po += __shfl_xor(po, 2);
        if (part == 0) out[nodeBase + n] = po * 0.25f + b4s[0];
    }
}

extern "C" void kernel_launch(void* const* d_in, const int* in_sizes, int n_in,
                              void* d_out, int out_size, void* d_ws, size_t ws_size,
                              hipStream_t stream) {
    const float* node_vec = (const float*)d_in[0];
    const float* emb      = (const float*)d_in[1];
    const float* W1       = (const float*)d_in[2];
    const float* b1v      = (const float*)d_in[5];
    const float* W2       = (const float*)d_in[6];
    const float* b2v      = (const float*)d_in[7];
    const float* W3       = (const float*)d_in[8];
    const float* b3v      = (const float*)d_in[9];
    const float* W4       = (const float*)d_in[10];
    const float* b4v      = (const float*)d_in[11];

    unsigned short* W1T = (unsigned short*)d_ws;        // 64*4096 u16 = 512 KB
    unsigned short* W2T = W1T + 64 * 4096;              // 64*512  u16 =  64 KB
    float* out = (float*)d_out;

    prep_kernel<<<64, 256, 0, stream>>>(W1, W2, W1T, W2T);
    main_kernel<<<256, 256, 0, stream>>>(node_vec, emb, W1T, W2T,
                                         b1v, b2v, W3, b3v, W4, b4v, out);
}

// Round 3
// 115.845 us; speedup vs baseline: 1.1709x; 1.1709x over previous
//
#include <hip/hip_runtime.h>
#include <hip/hip_bf16.h>

// Reduced problem: out[n] depends only on x0 = node_vec[:, :128], emb, W1_l0[:, :, :128],
// b1[:128], W2, b2, W3, b3, W4, b4.  y1/y2/gates are dead code in the reference.
//
// R2 -> R3: latency/occupancy fix. 256 blocks x 1024 threads (16 waves = 4/SIMD, 50% occ),
// f16 MFMA + v_pk_mul_f16 A-frag packing, LDS ~58 KB (< 64 KB workgroup cap).

#define NKC 64              // 2048 / 32 K-steps for 16x16x32 MFMA

typedef _Float16 h8  __attribute__((ext_vector_type(8)));
typedef _Float16 h2  __attribute__((ext_vector_type(2)));
typedef float    f32x4 __attribute__((ext_vector_type(4)));

static __device__ __forceinline__ unsigned int pack2h(float a, float b) {
    h2 t = {(_Float16)a, (_Float16)b};
    return __builtin_bit_cast(unsigned int, t);
}
static __device__ __forceinline__ f32x4 mfma_h(uint4 a, uint4 b, f32x4 c) {
    return __builtin_amdgcn_mfma_f32_16x16x32_f16(
        __builtin_bit_cast(h8, a), __builtin_bit_cast(h8, b), c, 0, 0, 0);
}
// A-frag: element j = xh * ee[j-range];  k = q*8+j, value = x0[m,i]*e[a]
static __device__ __forceinline__ uint4 mk_afrag(_Float16 xh, const h2* ee) {
    h2 xx = {xh, xh};
    uint4 r;
    r.x = __builtin_bit_cast(unsigned int, (h2)(xx * ee[0]));
    r.y = __builtin_bit_cast(unsigned int, (h2)(xx * ee[1]));
    r.z = __builtin_bit_cast(unsigned int, (h2)(xx * ee[2]));
    r.w = __builtin_bit_cast(unsigned int, (h2)(xx * ee[3]));
    return r;
}

// ---------------------------------------------------------------------------
// Prep: W1_l0 (keep cols 0..127) and W2 -> f16 B-fragment order:
//   W1T[kc][t][lane][j] = f16(W1[K = kc*32 + (lane>>4)*8 + j][t*16 + (lane&15)])
//   W2T[kc][lane][j]    = f16(W2[K][lane&15])
// Grid 256: block = kc*4 + tp; tp handles t in {tp*2, tp*2+1}.
// ---------------------------------------------------------------------------
__global__ __launch_bounds__(256) void prep_kernel(
        const float* __restrict__ W1, const float* __restrict__ W2,
        _Float16* __restrict__ W1T, _Float16* __restrict__ W2T) {
    const int b = blockIdx.x, kc = b >> 2, tp = b & 3;
    const int tid = threadIdx.x;
    __shared__ float l1[32 * 36];
    __shared__ float l2[32 * 20];

    {   // 32 rows x 32 cols sub-tile of W1 (cols tp*32 .. +32)
        int row = tid >> 3, c4 = tid & 7;
        float4 v = *(const float4*)(W1 + (size_t)(kc * 32 + row) * 224 + tp * 32 + c4 * 4);
        *(float4*)(l1 + row * 36 + c4 * 4) = v;
    }
    if (tp == 0 && tid < 128) {
        int row = tid >> 2, c4 = tid & 3;
        float4 v = *(const float4*)(W2 + (size_t)(kc * 32 + row) * 16 + c4 * 4);
        *(float4*)(l2 + row * 20 + c4 * 4) = v;
    }
    __syncthreads();

    if (tid < 128) {
        int tl = tid >> 6, t = tp * 2 + tl, lane = tid & 63;
        int q = lane >> 4, cc = lane & 15, colL = tl * 16 + cc;
        unsigned int w[4];
#pragma unroll
        for (int jj = 0; jj < 4; ++jj)
            w[jj] = pack2h(l1[(q * 8 + 2 * jj) * 36 + colL],
                           l1[(q * 8 + 2 * jj + 1) * 36 + colL]);
        *(uint4*)(W1T + (size_t)kc * 4096 + (t * 64 + lane) * 8) =
            make_uint4(w[0], w[1], w[2], w[3]);
    }
    if (tp == 0 && tid >= 128 && tid < 192) {
        int lane = tid - 128, q = lane >> 4, cc = lane & 15;
        unsigned int w[4];
#pragma unroll
        for (int jj = 0; jj < 4; ++jj)
            w[jj] = pack2h(l2[(q * 8 + 2 * jj) * 20 + cc],
                           l2[(q * 8 + 2 * jj + 1) * 20 + cc]);
        *(uint4*)(W2T + (size_t)kc * 512 + lane * 8) = make_uint4(w[0], w[1], w[2], w[3]);
    }
}

// ---------------------------------------------------------------------------
// Main: 64 nodes/block, 16 waves. Phase1: wave = (g = wave>>2) x (cs = wave&3):
// 16 nodes x 32 cols, full K. Phase2: (g, ks = wave&3): 16 nodes x 16 cols,
// K-quarter, LDS reduce. Phase3: 1024 threads.
// ---------------------------------------------------------------------------
__global__ __launch_bounds__(1024, 4) void main_kernel(
        const float* __restrict__ node_vec, const float* __restrict__ emb,
        const _Float16* __restrict__ W1T, const _Float16* __restrict__ W2T,
        const float* __restrict__ b1, const float* __restrict__ b2,
        const float* __restrict__ W3, const float* __restrict__ b3,
        const float* __restrict__ W4, const float* __restrict__ b4,
        float* __restrict__ out) {
    const int tid  = threadIdx.x;
    const int wave = tid >> 6, lane = tid & 63;
    const int q = lane >> 4, c = lane & 15;
    const int ihalf = q >> 1;
    const int g = wave >> 2;          // node-group (phase 1 & 2)
    const int cs = wave & 3;          // col-quarter (phase 1) / K-quarter (phase 2)
    const int nodeBase = blockIdx.x * 64;

    __shared__ _Float16 x0s[64 * 136];      // x0 tile f16, stride 136 halves
    __shared__ _Float16 scs[64 * 136];      // silu(s0) f16, stride 136
    __shared__ float    midp[4 * 64 * 17];  // phase-2 partials [ks][node][col]
    __shared__ float    mids[64 * 17];
    __shared__ float    w3s[256];
    __shared__ float    b3s[16];
    __shared__ float    w4s[16];
    __shared__ float    b4s[1];

    // stage x0 (cols 0..127) as f16
    for (int idx = tid; idx < 2048; idx += 1024) {
        int row = idx >> 5, c4 = idx & 31;
        float4 v = *(const float4*)(node_vec + (size_t)(nodeBase + row) * 480 + c4 * 4);
        unsigned int ua = pack2h(v.x, v.y), ub = pack2h(v.z, v.w);
        *(uint2*)(&x0s[row * 136 + c4 * 4]) = make_uint2(ua, ub);
    }
    if (tid < 256) w3s[tid] = W3[tid];
    if (tid < 16) { b3s[tid] = b3[tid]; w4s[tid] = W4[tid]; }
    if (tid == 0) b4s[0] = b4[0];

    // per-lane emb slice: node = nodeBase + g*16 + c, a = (q&1)*8 + j
    h2 ee[4];
    {
        const float* ep = emb + (size_t)(nodeBase + g * 16 + c) * 16 + (q & 1) * 8;
        float4 v0 = *(const float4*)ep;
        float4 v1 = *(const float4*)(ep + 4);
        ee[0] = (h2){(_Float16)v0.x, (_Float16)v0.y};
        ee[1] = (h2){(_Float16)v0.z, (_Float16)v0.w};
        ee[2] = (h2){(_Float16)v1.x, (_Float16)v1.y};
        ee[3] = (h2){(_Float16)v1.z, (_Float16)v1.w};
    }
    __syncthreads();

    // ---------------- Phase 1: 16 nodes x 32 cols per wave, full K
    f32x4 acc[2];
    acc[0] = (f32x4){0.f, 0.f, 0.f, 0.f};
    acc[1] = (f32x4){0.f, 0.f, 0.f, 0.f};

    const int rowA = g * 16 + c;
    const uint4* bptr = (const uint4*)W1T + lane;   // + (kc*8 + cs*2 + tt)*64
    const int cs2 = cs * 2;

    uint4 bb0[2], bb1[2];
    _Float16 xs0, xs1;
    bb0[0] = bptr[(cs2    ) * 64];
    bb0[1] = bptr[(cs2 + 1) * 64];
    xs0 = x0s[rowA * 136 + ihalf];

    for (int kc = 0; kc < NKC; kc += 2) {
        const int k1 = kc + 1;
        bb1[0] = bptr[(k1 * 8 + cs2    ) * 64];
        bb1[1] = bptr[(k1 * 8 + cs2 + 1) * 64];
        xs1 = x0s[rowA * 136 + 2 * k1 + ihalf];
        {
            uint4 af = mk_afrag(xs0, ee);
            acc[0] = mfma_h(af, bb0[0], acc[0]);
            acc[1] = mfma_h(af, bb0[1], acc[1]);
        }
        const int k2 = (kc + 2 < NKC) ? kc + 2 : 0;
        bb0[0] = bptr[(k2 * 8 + cs2    ) * 64];
        bb0[1] = bptr[(k2 * 8 + cs2 + 1) * 64];
        xs0 = x0s[rowA * 136 + 2 * k2 + ihalf];
        {
            uint4 af = mk_afrag(xs1, ee);
            acc[0] = mfma_h(af, bb1[0], acc[0]);
            acc[1] = mfma_h(af, bb1[1], acc[1]);
        }
    }

    // epilogue: silu -> f16 LDS.  C layout: col = c, row = q*4 + r.
    const float inv2048 = 0.022097086912079608f;   // 1/sqrt(128*16)
#pragma unroll
    for (int tt = 0; tt < 2; ++tt) {
        int t = cs2 + tt;
        float bb1v = b1[t * 16 + c];
#pragma unroll
        for (int r = 0; r < 4; ++r) {
            int node = g * 16 + q * 4 + r;
            float s  = acc[tt][r] * inv2048 + bb1v;
            float sc = s / (1.f + __expf(-s));
            scs[node * 136 + t * 16 + c] = (_Float16)sc;
        }
    }
    __syncthreads();

    // ---------------- Phase 2: (silu(s0) (x) emb) @ W2T, K-quarter per wave
    {
        const int ks = cs;
        const int rowS = g * 16 + c;
        const uint4* b2p = (const uint4*)W2T + lane;
        f32x4 macc = (f32x4){0.f, 0.f, 0.f, 0.f};
        const int kb = ks * 16;
        uint4 wb0, wb1;
        _Float16 sv0, sv1;
        wb0 = b2p[kb * 64];
        sv0 = scs[rowS * 136 + 2 * kb + ihalf];
        for (int u = 0; u < 16; u += 2) {
            const int kB = kb + u + 1;
            wb1 = b2p[kB * 64];
            sv1 = scs[rowS * 136 + 2 * kB + ihalf];
            macc = mfma_h(mk_afrag(sv0, ee), wb0, macc);
            const int kC = (u + 2 < 16) ? kb + u + 2 : kb;
            wb0 = b2p[kC * 64];
            sv0 = scs[rowS * 136 + 2 * kC + ihalf];
            macc = mfma_h(mk_afrag(sv1, ee), wb1, macc);
        }
#pragma unroll
        for (int r = 0; r < 4; ++r) {
            int node = g * 16 + q * 4 + r;
            midp[(ks * 64 + node) * 17 + c] = macc[r];
        }
    }
    __syncthreads();

    // reduce 4 K-quarters; 1024 threads = 64 nodes x 16 cols
    {
        int node = tid >> 4, col = tid & 15;
        float m = midp[node * 17 + col] + midp[(64 + node) * 17 + col]
                + midp[(128 + node) * 17 + col] + midp[(192 + node) * 17 + col];
        mids[node * 17 + col] = m * inv2048 + b2[col];
    }
    __syncthreads();

    // ---------------- Phase 3: h = silu(mid@W3/4 + b3); out = h@W4/4 + b4
    {
        int n = tid >> 4, jj = tid & 15;
        float a = 0.f;
#pragma unroll
        for (int cc = 0; cc < 16; ++cc) a += mids[n * 17 + cc] * w3s[cc * 16 + jj];
        a = a * 0.25f + b3s[jj];
        float hh = a / (1.f + __expf(-a));
        float po = hh * w4s[jj];
        po += __shfl_xor(po, 1);
        po += __shfl_xor(po, 2);
        po += __shfl_xor(po, 4);
        po += __shfl_xor(po, 8);
        if (jj == 0) out[nodeBase + n] = po * 0.25f + b4s[0];
    }
}

extern "C" void kernel_launch(void* const* d_in, const int* in_sizes, int n_in,
                              void* d_out, int out_size, void* d_ws, size_t ws_size,
                              hipStream_t stream) {
    const float* node_vec = (const float*)d_in[0];
    const float* emb      = (const float*)d_in[1];
    const float* W1       = (const float*)d_in[2];
    const float* b1v      = (const float*)d_in[5];
    const float* W2       = (const float*)d_in[6];
    const float* b2v      = (const float*)d_in[7];
    const float* W3       = (const float*)d_in[8];
    const float* b3v      = (const float*)d_in[9];
    const float* W4       = (const float*)d_in[10];
    const float* b4v      = (const float*)d_in[11];

    _Float16* W1T = (_Float16*)d_ws;          // 64*4096 halves = 512 KB
    _Float16* W2T = W1T + 64 * 4096;          // 64*512  halves =  64 KB
    float* out = (float*)d_out;

    prep_kernel<<<256, 256, 0, stream>>>(W1, W2, W1T, W2T);
    main_kernel<<<256, 1024, 0, stream>>>(node_vec, emb, W1T, W2T,
                                          b1v, b2v, W3, b3v, W4, b4v, out);
}